// Round 7
// baseline (167.415 us; speedup 1.0000x reference)
//
#include <hip/hip_runtime.h>
#include <hip/hip_bf16.h>

// Problem constants (fixed by setup_inputs)
#define BATCH  8
#define T_TOK  2048
#define DMODEL 1024
#define BT     (BATCH * T_TOK)   // 16384 tokens
#define NCOLS  96                // 64 activity + 32 time
#define KSPLIT 4                 // K-split factor: 4096 waves = 4/SIMD

typedef __bf16 bf16x8 __attribute__((ext_vector_type(8)));
typedef float  f32x4  __attribute__((ext_vector_type(4)));
typedef unsigned short u16x8 __attribute__((ext_vector_type(8)));

union AB { u16x8 u; bf16x8 b; unsigned int w[4]; };

__device__ __forceinline__ unsigned short f2bf(float f) {
    unsigned u = __float_as_uint(f);
    unsigned r = (u + 0x7fffu + ((u >> 16) & 1u)) >> 16;   // RNE
    return (unsigned short)r;
}
__device__ __forceinline__ float softplusf(float x) {
    return fmaxf(x, 0.f) + log1pf(expf(-fabsf(x)));
}
__device__ __forceinline__ float wave_sum(float v) {
#pragma unroll
    for (int o = 32; o > 0; o >>= 1) v += __shfl_xor(v, o, 64);
    return v;
}
// pack hi16(hi):hi16(lo) into one u32 (RTZ bf16 pair) — single v_perm
__device__ __forceinline__ unsigned int pack_rtz(float lo, float hi) {
    return __builtin_amdgcn_perm(__float_as_uint(hi), __float_as_uint(lo), 0x07060302u);
}
// hardware fp32 atomic add (global_atomic_add_f32, no CAS loop)
__device__ __forceinline__ void atomic_fadd(float* p, float v) {
    unsafeAtomicAdd(p, v);
}

// ---------------------------------------------------------------------------
// Kernel 1 (fused): blocks [0,384): Weff bf16 = W_next + sp(ts_a)*E[5+..] /
// W_time + sp(ts_t)*E[69+..].  Blocks [384,1920): init out with bias
// (float4 stores; bias = raw b_next/b_time, no softplus involved).
// ---------------------------------------------------------------------------
__global__ __launch_bounds__(256) void prep_init_kernel(
    const float* __restrict__ E,
    const float* __restrict__ Wn,
    const float* __restrict__ bn,
    const float* __restrict__ Wt,
    const float* __restrict__ bt,
    const float* __restrict__ tsa,
    const float* __restrict__ tst,
    unsigned short* __restrict__ Weff,
    float* __restrict__ out)
{
    const int blk = blockIdx.x;
    if (blk < 384) {
        int idx = blk * 256 + threadIdx.x;          // < 96*1024
        int row = idx >> 10, k = idx & 1023;
        float w;
        if (row < 64) {
            w = Wn[idx] + softplusf(tsa[0]) * E[(5 + row) * 1024 + k];
        } else {
            int c = row - 64;
            w = Wt[c * 1024 + k] + softplusf(tst[0]) * E[(69 + c) * 1024 + k];
        }
        Weff[idx] = f2bf(w);
    } else {
        int i = (blk - 384) * 256 + threadIdx.x;    // float4 index
        if (i < 262144) {                           // activity: 16384 x 64
            float4 b = reinterpret_cast<const float4*>(bn)[i & 15];
            reinterpret_cast<float4*>(out)[i] = b;
        } else {                                    // time: 16384 x 32
            int k = i - 262144;                     // < 131072
            float4 b = reinterpret_cast<const float4*>(bt)[k & 7];
            reinterpret_cast<float4*>(out)[i] = b;
        }
    }
}

// ---------------------------------------------------------------------------
// Kernel 2: K-split GEMM partial: out[t][j] += h[t][kr]·Weff[j][kr] over
// K-range kr = [blockIdx.y*256, +256).  MFMA 16x16x32 bf16, 1 wave = 16 tok
// x 96 cols, 8 K-iters fully unrolled (16 dwordx4 loads in flight).
// Accumulate into pre-biased out via HW fp32 atomics.
// D layout: col = lane&15, row = (lane>>4)*4 + reg  [m89/m91-verified].
// ---------------------------------------------------------------------------
__global__ __launch_bounds__(256) void gemm_kernel(
    const float* __restrict__ h,
    const unsigned short* __restrict__ Weff,
    float* __restrict__ out)
{
    const int lane = threadIdx.x & 63;
    const int wave = threadIdx.x >> 6;
    const int m = lane & 15;
    const int q = lane >> 4;
    const int tok_base = (blockIdx.x * 4 + wave) * 16;
    const int kbase = blockIdx.y * 32;              // in 8-elem chunks

    const float4* hA = reinterpret_cast<const float4*>(h + (size_t)(tok_base + m) * DMODEL);
    const bf16x8* wB = reinterpret_cast<const bf16x8*>(Weff + (size_t)m * DMODEL);

    f32x4 acc[6];
#pragma unroll
    for (int n = 0; n < 6; ++n) acc[n] = (f32x4){0.f, 0.f, 0.f, 0.f};

#pragma unroll
    for (int kc = 0; kc < 32; kc += 4) {            // ch = kbase+kc+q
        const int ch = kbase + kc + q;
        float4 f0 = hA[ch * 2];
        float4 f1 = hA[ch * 2 + 1];
        AB a;
        a.w[0] = pack_rtz(f0.x, f0.y);
        a.w[1] = pack_rtz(f0.z, f0.w);
        a.w[2] = pack_rtz(f1.x, f1.y);
        a.w[3] = pack_rtz(f1.z, f1.w);
#pragma unroll
        for (int n = 0; n < 6; ++n) {
            acc[n] = __builtin_amdgcn_mfma_f32_16x16x32_bf16(a.b, wB[n * 2048 + ch], acc[n], 0, 0, 0);
        }
    }

#pragma unroll
    for (int n = 0; n < 6; ++n) {
        const int j = n * 16 + m;
#pragma unroll
        for (int r = 0; r < 4; ++r) {
            const int t = tok_base + q * 4 + r;
            float* dst = (j < 64) ? &out[(size_t)t * 64 + j]
                                  : &out[(size_t)BT * 64 + (size_t)t * 32 + (j - 64)];
            atomic_fadd(dst, acc[n][r]);
        }
    }
}

// ---------------------------------------------------------------------------
// Kernel 3: copy/retrieval head, fp32 exact, atomicAdd directly into out.
// 64 blocks = 8 slices x 8 batches, deterministic ballot compaction.
// ---------------------------------------------------------------------------
__global__ __launch_bounds__(1024) void copy_kernel(
    const int* __restrict__ tokens,
    const float* __restrict__ h,
    const float* __restrict__ csa,
    const float* __restrict__ cst,
    const float* __restrict__ cta,
    const float* __restrict__ ctt,
    float* __restrict__ out)
{
    const int b     = blockIdx.x >> 3;
    const int slice = blockIdx.x & 7;
    const int tid  = threadIdx.x;
    const int wave = tid >> 6, lane = tid & 63;

    __shared__ int cnt_q[32], cnt_k[32], off_q[32], off_k[32];
    __shared__ int s_nq, s_nk;
    __shared__ int   q_pos[T_TOK];
    __shared__ int   k_pos[T_TOK];
    __shared__ int   k_col[T_TOK];
    __shared__ float q_nrm[T_TOK];
    __shared__ float k_nrm[T_TOK];

    const int* tk = tokens + b * T_TOK;

    // pass 1: per-64-chunk ballot counts (32 chunks, 2 per wave)
#pragma unroll
    for (int c = 0; c < 2; ++c) {
        int chunk = wave * 2 + c;
        int t = chunk * 64 + lane;
        int v = tk[t];
        bool pq = (v == 2);
        bool pk = (t > 0) && (tk[t - 1] == 2) && (v >= 5) && (v < 101);
        unsigned long long mq = __ballot(pq);
        unsigned long long mk = __ballot(pk);
        if (lane == 0) { cnt_q[chunk] = __popcll(mq); cnt_k[chunk] = __popcll(mk); }
    }
    __syncthreads();
    if (tid == 0) {
        int aq = 0, ak = 0;
        for (int i = 0; i < 32; ++i) {
            off_q[i] = aq; aq += cnt_q[i];
            off_k[i] = ak; ak += cnt_k[i];
        }
        s_nq = aq; s_nk = ak;
    }
    __syncthreads();

    // pass 2: sorted compaction via ballot rank
#pragma unroll
    for (int c = 0; c < 2; ++c) {
        int chunk = wave * 2 + c;
        int t = chunk * 64 + lane;
        int v = tk[t];
        bool pq = (v == 2);
        bool pk = (t > 0) && (tk[t - 1] == 2) && (v >= 5) && (v < 101);
        unsigned long long mq = __ballot(pq);
        unsigned long long mk = __ballot(pk);
        unsigned long long below = (lane == 0) ? 0ull : ((~0ull) >> (64 - lane));
        if (pq) q_pos[off_q[chunk] + __popcll(mq & below)] = t;
        if (pk) {
            int i = off_k[chunk] + __popcll(mk & below);
            k_pos[i] = t;
            k_col[i] = (v < 69) ? (v - 5) : (64 + (v - 69));
        }
    }
    __syncthreads();
    const int nq = s_nq, nk = s_nk;
    const float* hb = h + (size_t)b * T_TOK * DMODEL;

    // norms (one wave per row)
    for (int i = wave; i < nq + nk; i += 16) {
        const int row = (i < nq) ? q_pos[i] : k_pos[i - nq];
        const float4* p = reinterpret_cast<const float4*>(hb + (size_t)row * DMODEL);
        float s = 0.f;
#pragma unroll
        for (int c = 0; c < 4; ++c) {
            float4 v = p[lane + c * 64];
            s += v.x * v.x + v.y * v.y + v.z * v.z + v.w * v.w;
        }
        s = wave_sum(s);
        if (lane == 0) {
            float nn = fmaxf(sqrtf(s), 1e-12f);
            if (i < nq) q_nrm[i] = nn; else k_nrm[i - nq] = nn;
        }
    }
    __syncthreads();

    const float fa = softplusf(csa[0]) * softplusf(cta[0]);
    const float ft = softplusf(cst[0]) * softplusf(ctt[0]);
    const int P = nq * nk;
    const int g = slice * 16 + wave;              // global wave id in [0,128)
    for (int p = g; p < P; p += 128) {
        const int qi = p / nk, ki = p - qi * nk;
        const int qp = q_pos[qi], kp = k_pos[ki];
        if (kp >= qp) continue;                   // strict past (wave-uniform)
        const float4* pq = reinterpret_cast<const float4*>(hb + (size_t)qp * DMODEL);
        const float4* pk = reinterpret_cast<const float4*>(hb + (size_t)kp * DMODEL);
        float s = 0.f;
#pragma unroll
        for (int c = 0; c < 4; ++c) {
            float4 va = pq[lane + c * 64];
            float4 vb = pk[lane + c * 64];
            s += va.x * vb.x + va.y * vb.y + va.z * vb.z + va.w * vb.w;
        }
        s = wave_sum(s);
        if (lane == 0) {
            const int col = k_col[ki];
            const float val = ((col < 64) ? fa : ft) * (s / (q_nrm[qi] * k_nrm[ki]));
            const size_t tg = (size_t)b * T_TOK + qp;
            float* dst = (col < 64) ? &out[tg * 64 + col]
                                    : &out[(size_t)BT * 64 + tg * 32 + (col - 64)];
            atomic_fadd(dst, val);
        }
    }
}

// ---------------------------------------------------------------------------
// d_in (dict order): tokens, h, E, W_next, b_next, W_time, b_time,
//   tied_scale_act, tied_scale_time, copy_scale_act, copy_scale_time,
//   copy_temp_act, copy_temp_time.  fp32 inputs; fp32 output.
// ws: Weff bf16 @0 (192KB).
// ---------------------------------------------------------------------------
extern "C" void kernel_launch(void* const* d_in, const int* in_sizes, int n_in,
                              void* d_out, int out_size, void* d_ws, size_t ws_size,
                              hipStream_t stream) {
    const int* tokens = (const int*)d_in[0];
    const float* h    = (const float*)d_in[1];
    const float* E    = (const float*)d_in[2];
    const float* Wn   = (const float*)d_in[3];
    const float* bn   = (const float*)d_in[4];
    const float* Wt   = (const float*)d_in[5];
    const float* bt   = (const float*)d_in[6];
    const float* tsa  = (const float*)d_in[7];
    const float* tst  = (const float*)d_in[8];
    const float* csa  = (const float*)d_in[9];
    const float* cst  = (const float*)d_in[10];
    const float* cta  = (const float*)d_in[11];
    const float* ctt  = (const float*)d_in[12];

    unsigned short* Weff = (unsigned short*)d_ws;
    float* out           = (float*)d_out;

    prep_init_kernel<<<dim3(1920), dim3(256), 0, stream>>>(E, Wn, bn, Wt, bt, tsa, tst, Weff, out);
    gemm_kernel<<<dim3(BT / 64, KSPLIT), dim3(256), 0, stream>>>(h, Weff, out);
    copy_kernel<<<dim3(64), dim3(1024), 0, stream>>>(tokens, h, csa, cst, cta, ctt, out);
}

// Round 8
// 143.494 us; speedup vs baseline: 1.1667x; 1.1667x over previous
//
#include <hip/hip_runtime.h>
#include <hip/hip_bf16.h>

// Problem constants (fixed by setup_inputs)
#define BATCH  8
#define T_TOK  2048
#define DMODEL 1024
#define BT     (BATCH * T_TOK)   // 16384 tokens
#define NCOLS  96                // 64 activity + 32 time
#define KC     64                // K floats per chunk
#define NCHUNK (DMODEL / KC)     // 16

typedef __bf16 bf16x8 __attribute__((ext_vector_type(8)));
typedef float  f32x4  __attribute__((ext_vector_type(4)));
typedef unsigned short u16x8 __attribute__((ext_vector_type(8)));

union AB { u16x8 u; bf16x8 b; unsigned int w[4]; };

__device__ __forceinline__ unsigned short f2bf(float f) {
    unsigned u = __float_as_uint(f);
    unsigned r = (u + 0x7fffu + ((u >> 16) & 1u)) >> 16;   // RNE
    return (unsigned short)r;
}
__device__ __forceinline__ float softplusf(float x) {
    return fmaxf(x, 0.f) + log1pf(expf(-fabsf(x)));
}
__device__ __forceinline__ float wave_sum(float v) {
#pragma unroll
    for (int o = 32; o > 0; o >>= 1) v += __shfl_xor(v, o, 64);
    return v;
}
// pack hi16(hi):hi16(lo) into one u32 (RTZ bf16 pair) — single v_perm
__device__ __forceinline__ unsigned int pack_rtz(float lo, float hi) {
    return __builtin_amdgcn_perm(__float_as_uint(hi), __float_as_uint(lo), 0x07060302u);
}
__device__ __forceinline__ void atomic_fadd(float* p, float v) {
    unsafeAtomicAdd(p, v);   // global_atomic_add_f32
}
// async global->LDS, 16B per lane (zero VGPR round-trip, deep vmcnt queue)
__device__ __forceinline__ void async16(const void* g, void* l) {
    __builtin_amdgcn_global_load_lds(
        (const __attribute__((address_space(1))) unsigned int*)g,
        (__attribute__((address_space(3))) unsigned int*)l, 16, 0, 0);
}

// ---------------------------------------------------------------------------
// Kernel 1: Weff bf16 = W_next + sp(ts_a)*E[5+..] / W_time + sp(ts_t)*E[69+..]
// plus fp32 bias vector beff.
// ---------------------------------------------------------------------------
__global__ __launch_bounds__(256) void prep_kernel(
    const float* __restrict__ E,
    const float* __restrict__ Wn,
    const float* __restrict__ bn,
    const float* __restrict__ Wt,
    const float* __restrict__ bt,
    const float* __restrict__ tsa,
    const float* __restrict__ tst,
    unsigned short* __restrict__ Weff,
    float* __restrict__ beff)
{
    int idx = blockIdx.x * 256 + threadIdx.x;       // < 96*1024
    int row = idx >> 10, k = idx & 1023;
    float w;
    if (row < 64) {
        w = Wn[idx] + softplusf(tsa[0]) * E[(5 + row) * 1024 + k];
    } else {
        int c = row - 64;
        w = Wt[c * 1024 + k] + softplusf(tst[0]) * E[(69 + c) * 1024 + k];
    }
    Weff[idx] = f2bf(w);
    if (k == 0) beff[row] = (row < 64) ? bn[row] : bt[row - 64];
}

// ---------------------------------------------------------------------------
// Kernel 2: streaming MFMA GEMM, double-buffered async LDS staging.
// Block = 256 thr / 4 waves, M-tile 64 (wave w owns tokens tok0+w*16..+15),
// N = 96, K chunked by 64. LDS: A[64][16 f4] (col^ (row&7) swizzle),
// B[96][8 x16B] (same swizzle). One __syncthreads per chunk; stage(c+1)
// issued right after it so it streams during compute(c).
// D layout: col = lane&15, row = (lane>>4)*4 + reg  [m89/m91-verified].
// ---------------------------------------------------------------------------
__global__ __launch_bounds__(256) void gemm_kernel(
    const float* __restrict__ h,
    const unsigned short* __restrict__ Weff,
    const float* __restrict__ beff,
    float* __restrict__ out)
{
    __shared__ float4 Abuf[2][1024];   // 32 KB: [row][c4^(row&7)]
    __shared__ float4 Bbuf[2][768];    // 24 KB: [row][c16^(row&7)]

    const int tid  = threadIdx.x;
    const int lane = tid & 63;
    const int wave = tid >> 6;
    const int m = lane & 15;
    const int q = lane >> 4;
    const int tok0 = blockIdx.x * 64;

    f32x4 acc[6];
#pragma unroll
    for (int n = 0; n < 6; ++n) acc[n] = (f32x4){0.f, 0.f, 0.f, 0.f};

    const int r = wave * 16 + m;       // A row in tile
    const int s = m & 7;               // swizzle key (r&7 == m&7)

#define STAGE(cidx, buf)                                                        \
    {                                                                           \
        const int kb = (cidx) * KC;                                             \
        _Pragma("unroll")                                                       \
        for (int i = 0; i < 4; ++i) {                                           \
            int u = i * 256 + tid;                                              \
            int row_ = u >> 4, c4_ = u & 15;                                    \
            async16(h + (size_t)(tok0 + row_) * DMODEL + kb                     \
                        + ((c4_ ^ (row_ & 7)) << 2),                            \
                    &Abuf[buf][u]);                                             \
        }                                                                       \
        _Pragma("unroll")                                                       \
        for (int i = 0; i < 3; ++i) {                                           \
            int u = i * 256 + tid;                                              \
            int row_ = u >> 3, c16_ = u & 7;                                    \
            async16(Weff + (size_t)row_ * DMODEL + kb                           \
                         + ((c16_ ^ (row_ & 7)) << 3),                          \
                    &Bbuf[buf][u]);                                             \
        }                                                                       \
    }

    STAGE(0, 0);

    for (int c = 0; c < NCHUNK; ++c) {
        __syncthreads();                       // drains stage(c)
        if (c + 1 < NCHUNK) STAGE(c + 1, (c + 1) & 1);   // overlaps compute(c)
        const int buf = c & 1;
#pragma unroll
        for (int kk = 0; kk < 2; ++kk) {
            const int c4 = kk * 8 + q * 2;
            float4 f0 = Abuf[buf][r * 16 + ((c4    ) ^ s)];
            float4 f1 = Abuf[buf][r * 16 + ((c4 + 1) ^ s)];
            AB a;
            a.w[0] = pack_rtz(f0.x, f0.y);
            a.w[1] = pack_rtz(f0.z, f0.w);
            a.w[2] = pack_rtz(f1.x, f1.y);
            a.w[3] = pack_rtz(f1.z, f1.w);
#pragma unroll
            for (int n = 0; n < 6; ++n) {
                const int rb = n * 16 + m;
                const bf16x8* bp = reinterpret_cast<const bf16x8*>(
                    &Bbuf[buf][rb * 8 + ((kk * 4 + q) ^ s)]);
                acc[n] = __builtin_amdgcn_mfma_f32_16x16x32_bf16(a.b, *bp, acc[n], 0, 0, 0);
            }
        }
    }

#pragma unroll
    for (int n = 0; n < 6; ++n) {
        const int j = n * 16 + m;
        const float bj = beff[j];
#pragma unroll
        for (int rr = 0; rr < 4; ++rr) {
            const int t = tok0 + wave * 16 + q * 4 + rr;
            const float v = acc[n][rr] + bj;
            if (j < 64) out[(size_t)t * 64 + j] = v;
            else        out[(size_t)BT * 64 + (size_t)t * 32 + (j - 64)] = v;
        }
    }
#undef STAGE
}

// ---------------------------------------------------------------------------
// Kernel 3: copy/retrieval head, fp32 exact, atomics into out (after gemm).
// 64 blocks = 8 slices x 8 batches, deterministic ballot compaction.
// ---------------------------------------------------------------------------
__global__ __launch_bounds__(1024) void copy_kernel(
    const int* __restrict__ tokens,
    const float* __restrict__ h,
    const float* __restrict__ csa,
    const float* __restrict__ cst,
    const float* __restrict__ cta,
    const float* __restrict__ ctt,
    float* __restrict__ out)
{
    const int b     = blockIdx.x >> 3;
    const int slice = blockIdx.x & 7;
    const int tid  = threadIdx.x;
    const int wave = tid >> 6, lane = tid & 63;

    __shared__ int cnt_q[32], cnt_k[32], off_q[32], off_k[32];
    __shared__ int s_nq, s_nk;
    __shared__ int   q_pos[T_TOK];
    __shared__ int   k_pos[T_TOK];
    __shared__ int   k_col[T_TOK];
    __shared__ float q_nrm[T_TOK];
    __shared__ float k_nrm[T_TOK];

    const int* tk = tokens + b * T_TOK;

#pragma unroll
    for (int c = 0; c < 2; ++c) {
        int chunk = wave * 2 + c;
        int t = chunk * 64 + lane;
        int v = tk[t];
        bool pq = (v == 2);
        bool pk = (t > 0) && (tk[t - 1] == 2) && (v >= 5) && (v < 101);
        unsigned long long mq = __ballot(pq);
        unsigned long long mk = __ballot(pk);
        if (lane == 0) { cnt_q[chunk] = __popcll(mq); cnt_k[chunk] = __popcll(mk); }
    }
    __syncthreads();
    if (tid == 0) {
        int aq = 0, ak = 0;
        for (int i = 0; i < 32; ++i) {
            off_q[i] = aq; aq += cnt_q[i];
            off_k[i] = ak; ak += cnt_k[i];
        }
        s_nq = aq; s_nk = ak;
    }
    __syncthreads();

#pragma unroll
    for (int c = 0; c < 2; ++c) {
        int chunk = wave * 2 + c;
        int t = chunk * 64 + lane;
        int v = tk[t];
        bool pq = (v == 2);
        bool pk = (t > 0) && (tk[t - 1] == 2) && (v >= 5) && (v < 101);
        unsigned long long mq = __ballot(pq);
        unsigned long long mk = __ballot(pk);
        unsigned long long below = (lane == 0) ? 0ull : ((~0ull) >> (64 - lane));
        if (pq) q_pos[off_q[chunk] + __popcll(mq & below)] = t;
        if (pk) {
            int i = off_k[chunk] + __popcll(mk & below);
            k_pos[i] = t;
            k_col[i] = (v < 69) ? (v - 5) : (64 + (v - 69));
        }
    }
    __syncthreads();
    const int nq = s_nq, nk = s_nk;
    const float* hb = h + (size_t)b * T_TOK * DMODEL;

    for (int i = wave; i < nq + nk; i += 16) {
        const int row = (i < nq) ? q_pos[i] : k_pos[i - nq];
        const float4* p = reinterpret_cast<const float4*>(hb + (size_t)row * DMODEL);
        float ssum = 0.f;
#pragma unroll
        for (int c = 0; c < 4; ++c) {
            float4 v = p[lane + c * 64];
            ssum += v.x * v.x + v.y * v.y + v.z * v.z + v.w * v.w;
        }
        ssum = wave_sum(ssum);
        if (lane == 0) {
            float nn = fmaxf(sqrtf(ssum), 1e-12f);
            if (i < nq) q_nrm[i] = nn; else k_nrm[i - nq] = nn;
        }
    }
    __syncthreads();

    const float fa = softplusf(csa[0]) * softplusf(cta[0]);
    const float ft = softplusf(cst[0]) * softplusf(ctt[0]);
    const int P = nq * nk;
    const int g = slice * 16 + wave;              // global wave id in [0,128)
    for (int p = g; p < P; p += 128) {
        const int qi = p / nk, ki = p - qi * nk;
        const int qp = q_pos[qi], kp = k_pos[ki];
        if (kp >= qp) continue;                   // strict past (wave-uniform)
        const float4* pq = reinterpret_cast<const float4*>(hb + (size_t)qp * DMODEL);
        const float4* pk = reinterpret_cast<const float4*>(hb + (size_t)kp * DMODEL);
        float ssum = 0.f;
#pragma unroll
        for (int c = 0; c < 4; ++c) {
            float4 va = pq[lane + c * 64];
            float4 vb = pk[lane + c * 64];
            ssum += va.x * vb.x + va.y * vb.y + va.z * vb.z + va.w * vb.w;
        }
        ssum = wave_sum(ssum);
        if (lane == 0) {
            const int col = k_col[ki];
            const float val = ((col < 64) ? fa : ft) * (ssum / (q_nrm[qi] * k_nrm[ki]));
            const size_t tg = (size_t)b * T_TOK + qp;
            float* dst = (col < 64) ? &out[tg * 64 + col]
                                    : &out[(size_t)BT * 64 + tg * 32 + (col - 64)];
            atomic_fadd(dst, val);
        }
    }
}

// ---------------------------------------------------------------------------
// d_in (dict order): tokens, h, E, W_next, b_next, W_time, b_time,
//   tied_scale_act, tied_scale_time, copy_scale_act, copy_scale_time,
//   copy_temp_act, copy_temp_time.  fp32 inputs; fp32 output.
// ws: beff fp32 @0 | Weff bf16 @1024 (192KB).
// ---------------------------------------------------------------------------
extern "C" void kernel_launch(void* const* d_in, const int* in_sizes, int n_in,
                              void* d_out, int out_size, void* d_ws, size_t ws_size,
                              hipStream_t stream) {
    const int* tokens = (const int*)d_in[0];
    const float* h    = (const float*)d_in[1];
    const float* E    = (const float*)d_in[2];
    const float* Wn   = (const float*)d_in[3];
    const float* bn   = (const float*)d_in[4];
    const float* Wt   = (const float*)d_in[5];
    const float* bt   = (const float*)d_in[6];
    const float* tsa  = (const float*)d_in[7];
    const float* tst  = (const float*)d_in[8];
    const float* csa  = (const float*)d_in[9];
    const float* cst  = (const float*)d_in[10];
    const float* cta  = (const float*)d_in[11];
    const float* ctt  = (const float*)d_in[12];

    char* ws = (char*)d_ws;
    float* beff          = (float*)ws;
    unsigned short* Weff = (unsigned short*)(ws + 1024);
    float* out           = (float*)d_out;

    prep_kernel<<<dim3(384), dim3(256), 0, stream>>>(E, Wn, bn, Wt, bt, tsa, tst, Weff, beff);
    gemm_kernel<<<dim3(BT / 64), dim3(256), 0, stream>>>(h, Weff, beff, out);
    copy_kernel<<<dim3(64), dim3(1024), 0, stream>>>(tokens, h, csa, cst, cta, ctt, out);
}